// Round 11
// baseline (158.029 us; speedup 1.0000x reference)
//
#include <hip/hip_runtime.h>
#include <hip/hip_cooperative_groups.h>

namespace cg = cooperative_groups;

#define KP    96
#define NF    16
#define NCOL  117
#define PBLK  (KP * NF)   // 1536
#define NPB   64          // points per phase-1 chunk (32 lanes x 2)
#define NBLK  256
#define NTHR  768

// ===========================================================================
// FUSED cooperative kernel: phase1 (partial QF) -> sync -> phase2 (reduce)
// -> sync -> phase3 (out = F @ W, W = [I | QF^T | QF^T QF], 32-pt stages).
// ALL __syncthreads() are block-uniform (R10's NaN was a divergent barrier
// in phase 2 pairing with grid.sync()'s internal barrier).
// ===========================================================================
__global__ __launch_bounds__(NTHR, 3) void fused(
    const float* __restrict__ X, const float* __restrict__ F,
    const float* __restrict__ QX, const float* __restrict__ omegaD,
    const float* __restrict__ omegaF,
    int K, int nchunk, int nst,
    float* __restrict__ partial, float* __restrict__ QF,
    float* __restrict__ out)
{
    __shared__ __align__(16) float red[12 * 2 * 64];   // 6 KB (ph1 gather / ph2)
    __shared__ __align__(16) float WL[120 * 16];       // 7.5 KB (ph3 W^T rows)
    __shared__ __align__(16) float buf[2][32 * NCOL];  // 29.25 KB (ph3 stages)

    const int tid  = threadIdx.x;
    const int lane = tid & 63;

    // ---------------- phase 1: partial QF ----------------
    {
        const int oct = __builtin_amdgcn_readfirstlane(tid >> 6);  // 0..11
        const int fh  = lane >> 5;
        const int pl  = lane & 31;

        float4 qreg[8];
#pragma unroll
        for (int kk = 0; kk < 8; ++kk) {
            const int k = oct * 8 + kk;
            float4 v = make_float4(1.0e4f, 1.0e4f, 1.0e4f, -1.0f);
            if (k < K) {
                v.x = QX[k * 3 + 0];
                v.y = QX[k * 3 + 1];
                v.z = QX[k * 3 + 2];
                const float w = omegaD[k];
                v.w = 1.0f / (w * w);
            }
            qreg[kk] = v;
        }

        float acc[8][8];
#pragma unroll
        for (int a2 = 0; a2 < 8; ++a2)
#pragma unroll
            for (int b2 = 0; b2 < 8; ++b2) acc[a2][b2] = 0.f;

        int pb = blockIdx.x;
        float ax0 = 0.f, ax1 = 0.f, ax2 = 0.f, bx0 = 0.f, bx1 = 0.f, bx2 = 0.f;
        float4 faA = make_float4(0.f, 0.f, 0.f, 0.f), fbA = faA, faB = faA, fbB = faA;
        if (pb < nchunk) {
            const int pA = pb * NPB + pl;
            const int pB = pA + 32;
            ax0 = X[pA * 3 + 0]; ax1 = X[pA * 3 + 1]; ax2 = X[pA * 3 + 2];
            bx0 = X[pB * 3 + 0]; bx1 = X[pB * 3 + 1]; bx2 = X[pB * 3 + 2];
            faA = *reinterpret_cast<const float4*>(&F[(size_t)pA * NF + 8 * fh]);
            fbA = *reinterpret_cast<const float4*>(&F[(size_t)pA * NF + 8 * fh + 4]);
            faB = *reinterpret_cast<const float4*>(&F[(size_t)pB * NF + 8 * fh]);
            fbB = *reinterpret_cast<const float4*>(&F[(size_t)pB * NF + 8 * fh + 4]);
        }
        while (pb < nchunk) {
            const int pn = pb + NBLK;
            float nax0 = 0.f, nax1 = 0.f, nax2 = 0.f, nbx0 = 0.f, nbx1 = 0.f, nbx2 = 0.f;
            float4 nfaA = make_float4(0.f, 0.f, 0.f, 0.f), nfbA = nfaA, nfaB = nfaA, nfbB = nfaA;
            if (pn < nchunk) {
                const int pA = pn * NPB + pl;
                const int pB = pA + 32;
                nax0 = X[pA * 3 + 0]; nax1 = X[pA * 3 + 1]; nax2 = X[pA * 3 + 2];
                nbx0 = X[pB * 3 + 0]; nbx1 = X[pB * 3 + 1]; nbx2 = X[pB * 3 + 2];
                nfaA = *reinterpret_cast<const float4*>(&F[(size_t)pA * NF + 8 * fh]);
                nfbA = *reinterpret_cast<const float4*>(&F[(size_t)pA * NF + 8 * fh + 4]);
                nfaB = *reinterpret_cast<const float4*>(&F[(size_t)pB * NF + 8 * fh]);
                nfbB = *reinterpret_cast<const float4*>(&F[(size_t)pB * NF + 8 * fh + 4]);
            }
            {
                float e[8];
#pragma unroll
                for (int kk = 0; kk < 8; ++kk) {
                    const float4 q = qreg[kk];
                    const float dx = ax0 - q.x, dy = ax1 - q.y, dz = ax2 - q.z;
                    e[kk] = __expf((dx * dx + dy * dy + dz * dz) * q.w);
                }
                const float fv[8] = {faA.x, faA.y, faA.z, faA.w, fbA.x, fbA.y, fbA.z, fbA.w};
#pragma unroll
                for (int kk = 0; kk < 8; ++kk)
#pragma unroll
                    for (int u = 0; u < 8; ++u) acc[kk][u] += e[kk] * fv[u];
            }
            {
                float e[8];
#pragma unroll
                for (int kk = 0; kk < 8; ++kk) {
                    const float4 q = qreg[kk];
                    const float dx = bx0 - q.x, dy = bx1 - q.y, dz = bx2 - q.z;
                    e[kk] = __expf((dx * dx + dy * dy + dz * dz) * q.w);
                }
                const float fv[8] = {faB.x, faB.y, faB.z, faB.w, fbB.x, fbB.y, fbB.z, fbB.w};
#pragma unroll
                for (int kk = 0; kk < 8; ++kk)
#pragma unroll
                    for (int u = 0; u < 8; ++u) acc[kk][u] += e[kk] * fv[u];
            }
            ax0 = nax0; ax1 = nax1; ax2 = nax2; faA = nfaA; fbA = nfbA;
            bx0 = nbx0; bx1 = nbx1; bx2 = nbx2; faB = nfaB; fbB = nfbB;
            pb = pn;
        }

#pragma unroll
        for (int m = 1; m <= 16; m <<= 1) {
#pragma unroll
            for (int a2 = 0; a2 < 8; ++a2)
#pragma unroll
                for (int b2 = 0; b2 < 8; ++b2)
                    acc[a2][b2] += __shfl_xor(acc[a2][b2], m);
        }
        if (pl == 0) {
            float* rp = &red[oct * 128 + fh * 64];
#pragma unroll
            for (int a2 = 0; a2 < 8; ++a2) {
                *reinterpret_cast<float4*>(&rp[a2 * 8]) =
                    make_float4(acc[a2][0], acc[a2][1], acc[a2][2], acc[a2][3]);
                *reinterpret_cast<float4*>(&rp[a2 * 8 + 4]) =
                    make_float4(acc[a2][4], acc[a2][5], acc[a2][6], acc[a2][7]);
            }
        }
        __syncthreads();
        float* pbase = partial + (size_t)blockIdx.x * PBLK;
        for (int idx = tid; idx < PBLK; idx += NTHR) {
            const int o2 = idx >> 7;
            const int r  = idx & 127;
            const int kk = r >> 4;
            const int f  = r & 15;
            pbase[idx] = red[o2 * 128 + (f >> 3) * 64 + kk * 8 + (f & 7)];
        }
    }

    cg::this_grid().sync();

    // ---------------- phase 2: reduce partials -> QF (uniform barriers) ----
    if (blockIdx.x < KP) {
        const int k = blockIdx.x;
        if (tid < 256) {
            const int f = tid & 15, g = tid >> 4;
            float s = 0.f;
            for (int b = g; b < NBLK; b += 16)
                s += partial[(size_t)b * PBLK + k * NF + f];
            red[g * 17 + f] = s;   // red reused as [16][17]
        }
        __syncthreads();           // block-uniform
        if (tid < 16) {
            float t = 0.f;
#pragma unroll
            for (int g2 = 0; g2 < 16; ++g2) t += red[g2 * 17 + tid];
            QF[k * NF + tid] = t * omegaF[tid];
        }
    }

    cg::this_grid().sync();

    // ---------------- phase 3: out = F @ W ----------------
    // WL[c][u] = W[u][c]:  c<16: I;  16..100: QF rows;  101..116: B2; 117..119: 0
    for (int idx = tid; idx < 16 * 16; idx += NTHR) {
        const int c = idx >> 4, u = idx & 15;
        WL[c * 16 + u] = (c == u) ? 1.f : 0.f;
    }
    for (int idx = tid; idx < 85 * 16; idx += NTHR)
        WL[(16 + (idx >> 4)) * 16 + (idx & 15)] = QF[idx];
    for (int idx = tid; idx < 3 * 16; idx += NTHR)
        WL[(117 + (idx >> 4)) * 16 + (idx & 15)] = 0.f;
    __syncthreads();
    if (tid < 256) {   // B2[v][u]; WL[101+u][v] = B2[v][u]
        const int u = tid & 15, v = tid >> 4;
        float s = 0.f;
        for (int k = 0; k < 85; ++k)
            s += WL[(16 + k) * 16 + v] * WL[(16 + k) * 16 + u];
        WL[(101 + u) * 16 + v] = s;
    }
    __syncthreads();

    const int pp = tid & 31;   // point slot
    const int q  = tid >> 5;   // 0..23, owns cols q*5 .. q*5+4
    float w[5][NF];
#pragma unroll
    for (int s = 0; s < 5; ++s) {
        const int c = q * 5 + s;   // <= 119
#pragma unroll
        for (int u = 0; u < NF; ++u) w[s][u] = WL[c * 16 + u];
    }

    int s0 = blockIdx.x;
    float4 f0, f1, f2, f3;
    if (s0 < nst) {
        const float4* Fv = reinterpret_cast<const float4*>(F + (size_t)(s0 * 32 + pp) * NF);
        f0 = Fv[0]; f1 = Fv[1]; f2 = Fv[2]; f3 = Fv[3];
    }
    int it = 0;
    while (s0 < nst) {
        const int sn = s0 + NBLK;
        float4 n0, n1, n2, n3;
        if (sn < nst) {
            const float4* Fv = reinterpret_cast<const float4*>(F + (size_t)(sn * 32 + pp) * NF);
            n0 = Fv[0]; n1 = Fv[1]; n2 = Fv[2]; n3 = Fv[3];
        }
        float fr[NF];
        fr[0]  = f0.x; fr[1]  = f0.y; fr[2]  = f0.z; fr[3]  = f0.w;
        fr[4]  = f1.x; fr[5]  = f1.y; fr[6]  = f1.z; fr[7]  = f1.w;
        fr[8]  = f2.x; fr[9]  = f2.y; fr[10] = f2.z; fr[11] = f2.w;
        fr[12] = f3.x; fr[13] = f3.y; fr[14] = f3.z; fr[15] = f3.w;

        float* bp = &buf[it & 1][pp * NCOL];
#pragma unroll
        for (int s = 0; s < 5; ++s) {
            const int c = q * 5 + s;
            float t = 0.f;
#pragma unroll
            for (int u = 0; u < NF; ++u) t += fr[u] * w[s][u];
            if (c < NCOL) bp[c] = t;
        }
        __syncthreads();
        {
            float4* dst = reinterpret_cast<float4*>(out + (size_t)s0 * 32 * NCOL);
            const float4* src = reinterpret_cast<const float4*>(buf[it & 1]);
            for (int t2 = tid; t2 < (32 * NCOL) / 4; t2 += NTHR) dst[t2] = src[t2];
        }
        f0 = n0; f1 = n1; f2 = n2; f3 = n3;
        s0 = sn; ++it;
    }
}

// ===========================================================================
// Fallback path (R9 kernels) if cooperative launch is unavailable.
// ===========================================================================
__global__ __launch_bounds__(768, 3) void k1_partial(
    const float* __restrict__ X, const float* __restrict__ F,
    const float* __restrict__ QX, const float* __restrict__ omegaD,
    int K, int nchunk, float* __restrict__ partial)
{
    __shared__ __align__(16) float red[12 * 2 * 64];
    const int tid  = threadIdx.x;
    const int lane = tid & 63;
    const int oct  = __builtin_amdgcn_readfirstlane(tid >> 6);
    const int fh   = lane >> 5;
    const int pl   = lane & 31;
    float4 qreg[8];
#pragma unroll
    for (int kk = 0; kk < 8; ++kk) {
        const int k = oct * 8 + kk;
        float4 v = make_float4(1.0e4f, 1.0e4f, 1.0e4f, -1.0f);
        if (k < K) {
            v.x = QX[k * 3 + 0]; v.y = QX[k * 3 + 1]; v.z = QX[k * 3 + 2];
            const float w = omegaD[k];
            v.w = 1.0f / (w * w);
        }
        qreg[kk] = v;
    }
    float acc[8][8];
#pragma unroll
    for (int a2 = 0; a2 < 8; ++a2)
#pragma unroll
        for (int b2 = 0; b2 < 8; ++b2) acc[a2][b2] = 0.f;
    int pb = blockIdx.x;
    float ax0 = 0.f, ax1 = 0.f, ax2 = 0.f, bx0 = 0.f, bx1 = 0.f, bx2 = 0.f;
    float4 faA = make_float4(0.f, 0.f, 0.f, 0.f), fbA = faA, faB = faA, fbB = faA;
    if (pb < nchunk) {
        const int pA = pb * NPB + pl, pB = pA + 32;
        ax0 = X[pA * 3 + 0]; ax1 = X[pA * 3 + 1]; ax2 = X[pA * 3 + 2];
        bx0 = X[pB * 3 + 0]; bx1 = X[pB * 3 + 1]; bx2 = X[pB * 3 + 2];
        faA = *reinterpret_cast<const float4*>(&F[(size_t)pA * NF + 8 * fh]);
        fbA = *reinterpret_cast<const float4*>(&F[(size_t)pA * NF + 8 * fh + 4]);
        faB = *reinterpret_cast<const float4*>(&F[(size_t)pB * NF + 8 * fh]);
        fbB = *reinterpret_cast<const float4*>(&F[(size_t)pB * NF + 8 * fh + 4]);
    }
    while (pb < nchunk) {
        const int pn = pb + gridDim.x;
        float nax0 = 0.f, nax1 = 0.f, nax2 = 0.f, nbx0 = 0.f, nbx1 = 0.f, nbx2 = 0.f;
        float4 nfaA = make_float4(0.f, 0.f, 0.f, 0.f), nfbA = nfaA, nfaB = nfaA, nfbB = nfaA;
        if (pn < nchunk) {
            const int pA = pn * NPB + pl, pB = pA + 32;
            nax0 = X[pA * 3 + 0]; nax1 = X[pA * 3 + 1]; nax2 = X[pA * 3 + 2];
            nbx0 = X[pB * 3 + 0]; nbx1 = X[pB * 3 + 1]; nbx2 = X[pB * 3 + 2];
            nfaA = *reinterpret_cast<const float4*>(&F[(size_t)pA * NF + 8 * fh]);
            nfbA = *reinterpret_cast<const float4*>(&F[(size_t)pA * NF + 8 * fh + 4]);
            nfaB = *reinterpret_cast<const float4*>(&F[(size_t)pB * NF + 8 * fh]);
            nfbB = *reinterpret_cast<const float4*>(&F[(size_t)pB * NF + 8 * fh + 4]);
        }
        {
            float e[8];
#pragma unroll
            for (int kk = 0; kk < 8; ++kk) {
                const float4 q = qreg[kk];
                const float dx = ax0 - q.x, dy = ax1 - q.y, dz = ax2 - q.z;
                e[kk] = __expf((dx * dx + dy * dy + dz * dz) * q.w);
            }
            const float fv[8] = {faA.x, faA.y, faA.z, faA.w, fbA.x, fbA.y, fbA.z, fbA.w};
#pragma unroll
            for (int kk = 0; kk < 8; ++kk)
#pragma unroll
                for (int u = 0; u < 8; ++u) acc[kk][u] += e[kk] * fv[u];
        }
        {
            float e[8];
#pragma unroll
            for (int kk = 0; kk < 8; ++kk) {
                const float4 q = qreg[kk];
                const float dx = bx0 - q.x, dy = bx1 - q.y, dz = bx2 - q.z;
                e[kk] = __expf((dx * dx + dy * dy + dz * dz) * q.w);
            }
            const float fv[8] = {faB.x, faB.y, faB.z, faB.w, fbB.x, fbB.y, fbB.z, fbB.w};
#pragma unroll
            for (int kk = 0; kk < 8; ++kk)
#pragma unroll
                for (int u = 0; u < 8; ++u) acc[kk][u] += e[kk] * fv[u];
        }
        ax0 = nax0; ax1 = nax1; ax2 = nax2; faA = nfaA; fbA = nfbA;
        bx0 = nbx0; bx1 = nbx1; bx2 = nbx2; faB = nfaB; fbB = nfbB;
        pb = pn;
    }
#pragma unroll
    for (int m = 1; m <= 16; m <<= 1) {
#pragma unroll
        for (int a2 = 0; a2 < 8; ++a2)
#pragma unroll
            for (int b2 = 0; b2 < 8; ++b2)
                acc[a2][b2] += __shfl_xor(acc[a2][b2], m);
    }
    if (pl == 0) {
        float* rp = &red[oct * 128 + fh * 64];
#pragma unroll
        for (int a2 = 0; a2 < 8; ++a2) {
            *reinterpret_cast<float4*>(&rp[a2 * 8]) =
                make_float4(acc[a2][0], acc[a2][1], acc[a2][2], acc[a2][3]);
            *reinterpret_cast<float4*>(&rp[a2 * 8 + 4]) =
                make_float4(acc[a2][4], acc[a2][5], acc[a2][6], acc[a2][7]);
        }
    }
    __syncthreads();
    float* pbase = partial + (size_t)blockIdx.x * PBLK;
    for (int idx = tid; idx < PBLK; idx += 768) {
        const int o2 = idx >> 7, r = idx & 127, kk = r >> 4, f = r & 15;
        pbase[idx] = red[o2 * 128 + (f >> 3) * 64 + kk * 8 + (f & 7)];
    }
}

__global__ __launch_bounds__(256) void k1_reduce(
    const float* __restrict__ partial, const float* __restrict__ omegaF,
    int nb, float* __restrict__ QF)
{
    const int k = blockIdx.x, tid = threadIdx.x;
    const int f = tid & 15, g = tid >> 4;
    float s = 0.f;
    for (int b = g; b < nb; b += 16)
        s += partial[(size_t)b * PBLK + k * NF + f];
    __shared__ float red[16][17];
    red[g][f] = s;
    __syncthreads();
    if (tid < 16) {
        float t = 0.f;
#pragma unroll
        for (int g2 = 0; g2 < 16; ++g2) t += red[g2][tid];
        QF[k * NF + tid] = t * omegaF[tid];
    }
}

__global__ __launch_bounds__(256) void k1_b2(
    const float* __restrict__ QF, float* __restrict__ B2)
{
    __shared__ float qf[85 * 16];
    const int tid = threadIdx.x;
    for (int i = tid; i < 85 * 16; i += 256) qf[i] = QF[i];
    __syncthreads();
    const int u = tid & 15, v = tid >> 4;
    float s = 0.f;
    for (int k = 0; k < 85; ++k) s += qf[k * 16 + v] * qf[k * 16 + u];
    B2[v * 16 + u] = s;
}

__global__ __launch_bounds__(256, 4) void k2_out(
    const float* __restrict__ F, const float* __restrict__ QFb,
    const float* __restrict__ B2, float* __restrict__ out)
{
    __shared__ __align__(16) float row[2][32 * NCOL];
    const int tid = threadIdx.x;
    const int q = tid & 31, pp = tid >> 5;
    float qr[3][NF];
#pragma unroll
    for (int j = 0; j < 3; ++j) {
        const int k = q + 32 * j;
        if (k < 85) {
            const float4* qv = reinterpret_cast<const float4*>(QFb + (size_t)k * NF);
#pragma unroll
            for (int u2 = 0; u2 < 4; ++u2) {
                const float4 t4 = qv[u2];
                qr[j][4 * u2 + 0] = t4.x; qr[j][4 * u2 + 1] = t4.y;
                qr[j][4 * u2 + 2] = t4.z; qr[j][4 * u2 + 3] = t4.w;
            }
        } else {
#pragma unroll
            for (int u2 = 0; u2 < NF; ++u2) qr[j][u2] = 0.f;
        }
    }
    float b2c[NF];
#pragma unroll
    for (int v = 0; v < NF; ++v) b2c[v] = B2[v * 16 + (q & 15)];
    const int chunk = blockIdx.x * 256;
#pragma unroll 2
    for (int st = 0; st < 8; ++st) {
        const int sbase = chunk + st * 32;
        float* bufp = row[st & 1];
        float fr[NF];
        {
            const float4* Fv = reinterpret_cast<const float4*>(F + (size_t)(sbase + pp) * NF);
            const float4 t0 = Fv[0], t1 = Fv[1], t2 = Fv[2], t3 = Fv[3];
            fr[0]=t0.x; fr[1]=t0.y; fr[2]=t0.z; fr[3]=t0.w;
            fr[4]=t1.x; fr[5]=t1.y; fr[6]=t1.z; fr[7]=t1.w;
            fr[8]=t2.x; fr[9]=t2.y; fr[10]=t2.z; fr[11]=t2.w;
            fr[12]=t3.x; fr[13]=t3.y; fr[14]=t3.z; fr[15]=t3.w;
        }
#pragma unroll
        for (int it = 0; it < 4; ++it) {
            float4 n0, n1, n2, n3;
            if (it < 3) {
                const float4* Fv = reinterpret_cast<const float4*>(
                    F + (size_t)(sbase + (it + 1) * 8 + pp) * NF);
                n0 = Fv[0]; n1 = Fv[1]; n2 = Fv[2]; n3 = Fv[3];
            }
            float* rp = &bufp[(it * 8 + pp) * NCOL];
#pragma unroll
            for (int j = 0; j < 3; ++j) {
                const int k = q + 32 * j;
                float t = 0.f;
#pragma unroll
                for (int u2 = 0; u2 < NF; ++u2) t += fr[u2] * qr[j][u2];
                if (k < 85) rp[16 + k] = t;
            }
            if (q == 0) {
#pragma unroll
                for (int u2 = 0; u2 < NF; ++u2) rp[u2] = fr[u2];
            }
            if (q < 16) {
                float g = 0.f;
#pragma unroll
                for (int v = 0; v < NF; ++v) g += fr[v] * b2c[v];
                rp[101 + q] = g;
            }
            if (it < 3) {
                fr[0]=n0.x; fr[1]=n0.y; fr[2]=n0.z; fr[3]=n0.w;
                fr[4]=n1.x; fr[5]=n1.y; fr[6]=n1.z; fr[7]=n1.w;
                fr[8]=n2.x; fr[9]=n2.y; fr[10]=n2.z; fr[11]=n2.w;
                fr[12]=n3.x; fr[13]=n3.y; fr[14]=n3.z; fr[15]=n3.w;
            }
        }
        __syncthreads();
        {
            float4* dst = reinterpret_cast<float4*>(out + (size_t)sbase * NCOL);
            const float4* src = reinterpret_cast<const float4*>(bufp);
            for (int t2 = tid; t2 < (32 * NCOL) / 4; t2 += 256) dst[t2] = src[t2];
        }
    }
}

// ---------------------------------------------------------------------------
extern "C" void kernel_launch(void* const* d_in, const int* in_sizes, int n_in,
                              void* d_out, int out_size, void* d_ws, size_t ws_size,
                              hipStream_t stream)
{
    const float* X      = (const float*)d_in[0];
    const float* F      = (const float*)d_in[1];
    const float* QX     = (const float*)d_in[2];
    const float* omegaD = (const float*)d_in[3];
    const float* omegaF = (const float*)d_in[4];
    float* out = (float*)d_out;

    const int M = in_sizes[0] / 3;       // 262144
    int K = in_sizes[3];                 // 85
    int nchunk = M / NPB;                // 4096
    int nst = M / 32;                    // 8192

    float* partial = (float*)d_ws;                       // [256][1536]
    float* QFbuf   = partial + (size_t)NBLK * PBLK;      // [1536]
    float* B2buf   = QFbuf + PBLK;                       // [256]

    void* args[] = {(void*)&X, (void*)&F, (void*)&QX, (void*)&omegaD,
                    (void*)&omegaF, (void*)&K, (void*)&nchunk, (void*)&nst,
                    (void*)&partial, (void*)&QFbuf, (void*)&out};
    hipError_t err = hipLaunchCooperativeKernel((void*)fused, dim3(NBLK), dim3(NTHR),
                                                args, 0, stream);
    if (err != hipSuccess) {
        // fallback: 4-kernel path (R9)
        hipLaunchKernelGGL(k1_partial, dim3(NBLK), dim3(768), 0, stream,
                           X, F, QX, omegaD, K, nchunk, partial);
        hipLaunchKernelGGL(k1_reduce, dim3(KP), dim3(256), 0, stream,
                           partial, omegaF, NBLK, QFbuf);
        hipLaunchKernelGGL(k1_b2, dim3(1), dim3(256), 0, stream,
                           QFbuf, B2buf);
        hipLaunchKernelGGL(k2_out, dim3(M / 256), dim3(256), 0, stream,
                           F, QFbuf, B2buf, out);
    }
}

// Round 12
// 77.083 us; speedup vs baseline: 2.0501x; 2.0501x over previous
//
#include <hip/hip_runtime.h>

#define KP    96      // K=85 padded to 96 = 12 octets
#define NF    16
#define NCOL  117     // 16 + 85 + 16 output columns
#define PBLK  (KP * NF)   // 1536 floats per partial block
#define NPB   64      // points per block-iteration (k1): 32 lanes x 2 points

// Raw hardware exp2 (v_exp_f32). HIP's __expf w/o -ffast-math lowers to the
// OCML accurate path (~20+ insts); this is 1 inst. log2e is folded into invw2.
__device__ __forceinline__ float fast_exp2(float x) {
#if __has_builtin(__builtin_amdgcn_exp2f)
    return __builtin_amdgcn_exp2f(x);
#else
    float r;
    asm volatile("v_exp_f32 %0, %1" : "=v"(r) : "v"(x));
    return r;
#endif
}

// ---------------------------------------------------------------------------
// Kernel 1: wave-per-k-octet partial QF accumulation, 2 points/thread/iter.
// (R9 structure; exp via v_exp_f32 with log2e folded into invw2.)
// ---------------------------------------------------------------------------
__global__ __launch_bounds__(768, 3) void k1_partial(
    const float* __restrict__ X, const float* __restrict__ F,
    const float* __restrict__ QX, const float* __restrict__ omegaD,
    int K, int nchunk, float* __restrict__ partial)
{
    __shared__ __align__(16) float red[12 * 2 * 64];   // 6 KB

    const int tid  = threadIdx.x;
    const int lane = tid & 63;
    const int oct  = __builtin_amdgcn_readfirstlane(tid >> 6);  // wave id 0..11
    const int fh   = lane >> 5;     // f-half
    const int pl   = lane & 31;     // point lane

    float4 qreg[8];
#pragma unroll
    for (int kk = 0; kk < 8; ++kk) {
        const int k = oct * 8 + kk;
        float4 v = make_float4(1.0e4f, 1.0e4f, 1.0e4f, -1.0f);  // pad -> e=0
        if (k < K) {
            v.x = QX[k * 3 + 0];
            v.y = QX[k * 3 + 1];
            v.z = QX[k * 3 + 2];
            const float w = omegaD[k];
            v.w = 1.4426950408889634f / (w * w);   // log2(e)/w^2
        }
        qreg[kk] = v;
    }

    float acc[8][8];
#pragma unroll
    for (int a2 = 0; a2 < 8; ++a2)
#pragma unroll
        for (int b2 = 0; b2 < 8; ++b2) acc[a2][b2] = 0.f;

    int pb = blockIdx.x;
    float ax0 = 0.f, ax1 = 0.f, ax2 = 0.f, bx0 = 0.f, bx1 = 0.f, bx2 = 0.f;
    float4 faA = make_float4(0.f, 0.f, 0.f, 0.f), fbA = faA, faB = faA, fbB = faA;
    if (pb < nchunk) {
        const int pA = pb * NPB + pl, pB = pA + 32;
        ax0 = X[pA * 3 + 0]; ax1 = X[pA * 3 + 1]; ax2 = X[pA * 3 + 2];
        bx0 = X[pB * 3 + 0]; bx1 = X[pB * 3 + 1]; bx2 = X[pB * 3 + 2];
        faA = *reinterpret_cast<const float4*>(&F[(size_t)pA * NF + 8 * fh]);
        fbA = *reinterpret_cast<const float4*>(&F[(size_t)pA * NF + 8 * fh + 4]);
        faB = *reinterpret_cast<const float4*>(&F[(size_t)pB * NF + 8 * fh]);
        fbB = *reinterpret_cast<const float4*>(&F[(size_t)pB * NF + 8 * fh + 4]);
    }
    while (pb < nchunk) {
        const int pn = pb + gridDim.x;
        float nax0 = 0.f, nax1 = 0.f, nax2 = 0.f, nbx0 = 0.f, nbx1 = 0.f, nbx2 = 0.f;
        float4 nfaA = make_float4(0.f, 0.f, 0.f, 0.f), nfbA = nfaA, nfaB = nfaA, nfbB = nfaA;
        if (pn < nchunk) {
            const int pA = pn * NPB + pl, pB = pA + 32;
            nax0 = X[pA * 3 + 0]; nax1 = X[pA * 3 + 1]; nax2 = X[pA * 3 + 2];
            nbx0 = X[pB * 3 + 0]; nbx1 = X[pB * 3 + 1]; nbx2 = X[pB * 3 + 2];
            nfaA = *reinterpret_cast<const float4*>(&F[(size_t)pA * NF + 8 * fh]);
            nfbA = *reinterpret_cast<const float4*>(&F[(size_t)pA * NF + 8 * fh + 4]);
            nfaB = *reinterpret_cast<const float4*>(&F[(size_t)pB * NF + 8 * fh]);
            nfbB = *reinterpret_cast<const float4*>(&F[(size_t)pB * NF + 8 * fh + 4]);
        }

        // point A
        {
            float e[8];
#pragma unroll
            for (int kk = 0; kk < 8; ++kk) {
                const float4 q = qreg[kk];
                const float dx = ax0 - q.x, dy = ax1 - q.y, dz = ax2 - q.z;
                e[kk] = fast_exp2((dx * dx + dy * dy + dz * dz) * q.w);
            }
            const float fv[8] = {faA.x, faA.y, faA.z, faA.w, fbA.x, fbA.y, fbA.z, fbA.w};
#pragma unroll
            for (int kk = 0; kk < 8; ++kk)
#pragma unroll
                for (int u = 0; u < 8; ++u) acc[kk][u] += e[kk] * fv[u];
        }
        // point B
        {
            float e[8];
#pragma unroll
            for (int kk = 0; kk < 8; ++kk) {
                const float4 q = qreg[kk];
                const float dx = bx0 - q.x, dy = bx1 - q.y, dz = bx2 - q.z;
                e[kk] = fast_exp2((dx * dx + dy * dy + dz * dz) * q.w);
            }
            const float fv[8] = {faB.x, faB.y, faB.z, faB.w, fbB.x, fbB.y, fbB.z, fbB.w};
#pragma unroll
            for (int kk = 0; kk < 8; ++kk)
#pragma unroll
                for (int u = 0; u < 8; ++u) acc[kk][u] += e[kk] * fv[u];
        }

        ax0 = nax0; ax1 = nax1; ax2 = nax2; faA = nfaA; fbA = nfbA;
        bx0 = nbx0; bx1 = nbx1; bx2 = nbx2; faB = nfaB; fbB = nfbB;
        pb = pn;
    }

#pragma unroll
    for (int m = 1; m <= 16; m <<= 1) {
#pragma unroll
        for (int a2 = 0; a2 < 8; ++a2)
#pragma unroll
            for (int b2 = 0; b2 < 8; ++b2)
                acc[a2][b2] += __shfl_xor(acc[a2][b2], m);
    }
    if (pl == 0) {
        float* rp = &red[oct * 128 + fh * 64];
#pragma unroll
        for (int a2 = 0; a2 < 8; ++a2) {
            *reinterpret_cast<float4*>(&rp[a2 * 8]) =
                make_float4(acc[a2][0], acc[a2][1], acc[a2][2], acc[a2][3]);
            *reinterpret_cast<float4*>(&rp[a2 * 8 + 4]) =
                make_float4(acc[a2][4], acc[a2][5], acc[a2][6], acc[a2][7]);
        }
    }
    __syncthreads();
    float* pbase = partial + (size_t)blockIdx.x * PBLK;
    for (int idx = tid; idx < PBLK; idx += 768) {
        const int o2 = idx >> 7, r = idx & 127, kk = r >> 4, f = r & 15;
        pbase[idx] = red[o2 * 128 + (f >> 3) * 64 + kk * 8 + (f & 7)];
    }
}

// ---------------------------------------------------------------------------
// Kernel 1.5: fixed-order reduction of partials -> QF (applies omegaF).
// ---------------------------------------------------------------------------
__global__ __launch_bounds__(256) void k1_reduce(
    const float* __restrict__ partial, const float* __restrict__ omegaF,
    int nb, float* __restrict__ QF)
{
    const int k = blockIdx.x, tid = threadIdx.x;
    const int f = tid & 15, g = tid >> 4;
    float s = 0.f;
    for (int b = g; b < nb; b += 16)
        s += partial[(size_t)b * PBLK + k * NF + f];
    __shared__ float red[16][17];
    red[g][f] = s;
    __syncthreads();
    if (tid < 16) {
        float t = 0.f;
#pragma unroll
        for (int g2 = 0; g2 < 16; ++g2) t += red[g2][tid];
        QF[k * NF + tid] = t * omegaF[tid];
    }
}

// ---------------------------------------------------------------------------
// Kernel 1.75: B2 = QF^T @ QF  [16,16].
// ---------------------------------------------------------------------------
__global__ __launch_bounds__(256) void k1_b2(
    const float* __restrict__ QF, float* __restrict__ B2)
{
    __shared__ float qf[85 * 16];
    const int tid = threadIdx.x;
    for (int i = tid; i < 85 * 16; i += 256) qf[i] = QF[i];
    __syncthreads();
    const int u = tid & 15, v = tid >> 4;
    float s = 0.f;
    for (int k = 0; k < 85; ++k) s += qf[k * 16 + v] * qf[k * 16 + u];
    B2[v * 16 + u] = s;
}

// ---------------------------------------------------------------------------
// Kernel 2: double-buffered 32-row LDS stages (UNCHANGED from R9).
// ---------------------------------------------------------------------------
__global__ __launch_bounds__(256, 4) void k2_out(
    const float* __restrict__ F, const float* __restrict__ QFb,
    const float* __restrict__ B2, float* __restrict__ out)
{
    __shared__ __align__(16) float row[2][32 * NCOL];
    const int tid = threadIdx.x;
    const int q = tid & 31, pp = tid >> 5;
    float qr[3][NF];
#pragma unroll
    for (int j = 0; j < 3; ++j) {
        const int k = q + 32 * j;
        if (k < 85) {
            const float4* qv = reinterpret_cast<const float4*>(QFb + (size_t)k * NF);
#pragma unroll
            for (int u2 = 0; u2 < 4; ++u2) {
                const float4 t4 = qv[u2];
                qr[j][4 * u2 + 0] = t4.x; qr[j][4 * u2 + 1] = t4.y;
                qr[j][4 * u2 + 2] = t4.z; qr[j][4 * u2 + 3] = t4.w;
            }
        } else {
#pragma unroll
            for (int u2 = 0; u2 < NF; ++u2) qr[j][u2] = 0.f;
        }
    }
    float b2c[NF];
#pragma unroll
    for (int v = 0; v < NF; ++v) b2c[v] = B2[v * 16 + (q & 15)];
    const int chunk = blockIdx.x * 256;
#pragma unroll 2
    for (int st = 0; st < 8; ++st) {
        const int sbase = chunk + st * 32;
        float* bufp = row[st & 1];
        float fr[NF];
        {
            const float4* Fv = reinterpret_cast<const float4*>(F + (size_t)(sbase + pp) * NF);
            const float4 t0 = Fv[0], t1 = Fv[1], t2 = Fv[2], t3 = Fv[3];
            fr[0]=t0.x; fr[1]=t0.y; fr[2]=t0.z; fr[3]=t0.w;
            fr[4]=t1.x; fr[5]=t1.y; fr[6]=t1.z; fr[7]=t1.w;
            fr[8]=t2.x; fr[9]=t2.y; fr[10]=t2.z; fr[11]=t2.w;
            fr[12]=t3.x; fr[13]=t3.y; fr[14]=t3.z; fr[15]=t3.w;
        }
#pragma unroll
        for (int it = 0; it < 4; ++it) {
            float4 n0, n1, n2, n3;
            if (it < 3) {
                const float4* Fv = reinterpret_cast<const float4*>(
                    F + (size_t)(sbase + (it + 1) * 8 + pp) * NF);
                n0 = Fv[0]; n1 = Fv[1]; n2 = Fv[2]; n3 = Fv[3];
            }
            float* rp = &bufp[(it * 8 + pp) * NCOL];
#pragma unroll
            for (int j = 0; j < 3; ++j) {
                const int k = q + 32 * j;
                float t = 0.f;
#pragma unroll
                for (int u2 = 0; u2 < NF; ++u2) t += fr[u2] * qr[j][u2];
                if (k < 85) rp[16 + k] = t;
            }
            if (q == 0) {
#pragma unroll
                for (int u2 = 0; u2 < NF; ++u2) rp[u2] = fr[u2];
            }
            if (q < 16) {
                float g = 0.f;
#pragma unroll
                for (int v = 0; v < NF; ++v) g += fr[v] * b2c[v];
                rp[101 + q] = g;
            }
            if (it < 3) {
                fr[0]=n0.x; fr[1]=n0.y; fr[2]=n0.z; fr[3]=n0.w;
                fr[4]=n1.x; fr[5]=n1.y; fr[6]=n1.z; fr[7]=n1.w;
                fr[8]=n2.x; fr[9]=n2.y; fr[10]=n2.z; fr[11]=n2.w;
                fr[12]=n3.x; fr[13]=n3.y; fr[14]=n3.z; fr[15]=n3.w;
            }
        }
        __syncthreads();
        {
            float4* dst = reinterpret_cast<float4*>(out + (size_t)sbase * NCOL);
            const float4* src = reinterpret_cast<const float4*>(bufp);
            for (int t2 = tid; t2 < (32 * NCOL) / 4; t2 += 256) dst[t2] = src[t2];
        }
    }
}

// ---------------------------------------------------------------------------
extern "C" void kernel_launch(void* const* d_in, const int* in_sizes, int n_in,
                              void* d_out, int out_size, void* d_ws, size_t ws_size,
                              hipStream_t stream)
{
    const float* X      = (const float*)d_in[0];
    const float* F      = (const float*)d_in[1];
    const float* QX     = (const float*)d_in[2];
    const float* omegaD = (const float*)d_in[3];
    const float* omegaF = (const float*)d_in[4];
    float* out = (float*)d_out;

    const int M = in_sizes[0] / 3;       // 262144
    const int K = in_sizes[3];           // 85
    const int nchunk = M / NPB;          // 4096

    int nb = (int)((ws_size / sizeof(float) - PBLK - 256) / PBLK);
    if (nb > 256) nb = 256;              // 1 block/CU (12 waves)
    if (nb > nchunk) nb = nchunk;
    if (nb < 1) nb = 1;

    float* partial = (float*)d_ws;
    float* QFbuf   = partial + (size_t)nb * PBLK;
    float* B2buf   = QFbuf + PBLK;

    hipLaunchKernelGGL(k1_partial, dim3(nb), dim3(768), 0, stream,
                       X, F, QX, omegaD, K, nchunk, partial);
    hipLaunchKernelGGL(k1_reduce, dim3(KP), dim3(256), 0, stream,
                       partial, omegaF, nb, QFbuf);
    hipLaunchKernelGGL(k1_b2, dim3(1), dim3(256), 0, stream,
                       QFbuf, B2buf);
    hipLaunchKernelGGL(k2_out, dim3(M / 256), dim3(256), 0, stream,
                       F, QFbuf, B2buf, out);
}